// Round 1
// baseline (467.380 us; speedup 1.0000x reference)
//
#include <hip/hip_runtime.h>
#include <hip/hip_bf16.h>

// Sizes
#define NBATCH 128   // conv channels (o and c dims)
#define NSLIDE 256   // s dim (GEMM M total)
#define NDEMB  128   // d dim
#define NSLOT  33    // conv partial slots: h1:18 (k*3+p), h2:18+2k+p, h3:28+k
#define CCHUNKS 8
#define CPER    (NBATCH / CCHUNKS)   // 16 channels per chunk
#define KCHUNK  (CPER * NDEMB)       // 2048 contraction elements per wg
#define BM 128
#define BN 128
#define BK 32
#define NIT (KCHUNK / BK)            // 64
#define LDK (BK + 8)                 // padded LDS row stride (bf16 elems) = 40
#define CONV_ELEMS (NSLOT * NSLIDE * NBATCH)  // 1,081,344 floats

using ushort8 = __attribute__((ext_vector_type(8))) unsigned short;
using bf16x8  = __attribute__((ext_vector_type(8))) __bf16;
using floatx4 = __attribute__((ext_vector_type(4))) float;

// 53 unit GEMMs, ordered l-major so concurrently-dispatched wgs share A_l via L2/LLC.
// unit: conv[slot] += A_l(256x2048 chunk) * W_h[k,:,:,a,:]^T
__device__ __constant__ unsigned char U_L[53] = {
  0,0,0,0,0,0,0,0,0,0,0,0,0,0,0,0,
  1,1,1,1,1,1,1,1,1,1,1,1,1,1,1,1,1,1,1,1,1,
  2,2,2,2,2,2,2,2,2,2,2,2,2,2,2,2};
__device__ __constant__ unsigned char U_H[53] = {
  0,0,0,0,0,0, 1,1,1,1,1, 2,2,2,2,2,
  0,0,0,0,0,0, 1,1,1,1,1, 1,1,1,1,1, 2,2,2,2,2,
  0,0,0,0,0,0, 1,1,1,1,1, 2,2,2,2,2};
__device__ __constant__ unsigned char U_K[53] = {
  0,1,2,3,4,5, 0,1,2,3,4, 0,1,2,3,4,
  0,1,2,3,4,5, 0,1,2,3,4, 0,1,2,3,4, 0,1,2,3,4,
  0,1,2,3,4,5, 0,1,2,3,4, 0,1,2,3,4};
__device__ __constant__ unsigned char U_A[53] = {
  0,0,0,0,0,0, 0,0,0,0,0, 0,0,0,0,0,
  0,0,0,0,0,0, 1,1,1,1,1, 0,0,0,0,0, 1,1,1,1,1,
  0,0,0,0,0,0, 1,1,1,1,1, 2,2,2,2,2};
__device__ __constant__ unsigned char U_SLOT[53] = {
  0,3,6,9,12,15, 18,20,22,24,26, 28,29,30,31,32,
  1,4,7,10,13,16, 18,20,22,24,26, 19,21,23,25,27, 28,29,30,31,32,
  2,5,8,11,14,17, 19,21,23,25,27, 28,29,30,31,32};

__device__ __forceinline__ unsigned short f2bf(float f) {
  union { float f; unsigned u; } v; v.f = f;
  unsigned r = v.u + 0x7fffu + ((v.u >> 16) & 1u);  // RNE (inputs finite)
  return (unsigned short)(r >> 16);
}

__global__ void zero_ws(float* __restrict__ p) {
  int i = blockIdx.x * 256 + threadIdx.x;   // one float4 each, grid sized exactly
  reinterpret_cast<float4*>(p)[i] = make_float4(0.f, 0.f, 0.f, 0.f);
}

__global__ __launch_bounds__(256, 2) void gemm_units(
    const float* __restrict__ Ec,
    const float* __restrict__ W1, const float* __restrict__ W2,
    const float* __restrict__ W3,
    float* __restrict__ conv)
{
  const int bx     = blockIdx.x;       // 0..105 = unit*2 + m_half
  const int cc     = blockIdx.y;       // 0..7
  const int unit   = bx >> 1;
  const int m_half = bx & 1;

  const int l     = U_L[unit];
  const int h_idx = U_H[unit];
  const int kker  = U_K[unit];
  const int aa    = U_A[unit];
  const int slot  = U_SLOT[unit];
  const int h     = h_idx + 1;

  const float* wbase = (h_idx == 0) ? W1 : ((h_idx == 1) ? W2 : W3);
  const long o_stride = 16384L * h;    // W element stride over o
  const long c_stride = 128L * h;      // W element stride over c
  const float* wp = wbase + (long)kker * (128L * o_stride) + (long)aa * 128;
  const int c0 = cc * CPER;

  __shared__ __align__(16) unsigned short As[BM][LDK];
  __shared__ __align__(16) unsigned short Bs[BN][LDK];

  const int tid   = threadIdx.x;
  const int srow  = tid >> 1;           // 0..127 staging row
  const int shalf = (tid & 1) * 16;     // first/second 16 k-elements

  // base pointers for staging loads (include shalf)
  const float* aBase = Ec + (long)l * 128 + (long)(m_half * 128 + srow) * 384 + shalf;
  const float* wBase = wp + (long)srow * o_stride + shalf;

  const int wave = tid >> 6;
  const int lane = tid & 63;
  const int wm = (wave >> 1) * 64;
  const int wn = (wave & 1) * 64;
  const int lr = lane & 15;
  const int lq = lane >> 4;

  floatx4 acc[4][4];
#pragma unroll
  for (int i = 0; i < 4; ++i)
#pragma unroll
    for (int j = 0; j < 4; ++j) acc[i][j] = (floatx4){0.f, 0.f, 0.f, 0.f};

  float4 aL[4], wL[4];
  {
    const int c = c0;            // it = 0
    const float4* ap4 = reinterpret_cast<const float4*>(aBase + (long)c * 98304);
    const float4* wp4 = reinterpret_cast<const float4*>(wBase + (long)c * c_stride);
#pragma unroll
    for (int q = 0; q < 4; ++q) { aL[q] = ap4[q]; wL[q] = wp4[q]; }
  }

  for (int it = 0; it < NIT; ++it) {
    __syncthreads();   // previous iteration's LDS reads complete
    {
      ushort8 pa0 = { f2bf(aL[0].x), f2bf(aL[0].y), f2bf(aL[0].z), f2bf(aL[0].w),
                      f2bf(aL[1].x), f2bf(aL[1].y), f2bf(aL[1].z), f2bf(aL[1].w) };
      ushort8 pa1 = { f2bf(aL[2].x), f2bf(aL[2].y), f2bf(aL[2].z), f2bf(aL[2].w),
                      f2bf(aL[3].x), f2bf(aL[3].y), f2bf(aL[3].z), f2bf(aL[3].w) };
      ushort8 pw0 = { f2bf(wL[0].x), f2bf(wL[0].y), f2bf(wL[0].z), f2bf(wL[0].w),
                      f2bf(wL[1].x), f2bf(wL[1].y), f2bf(wL[1].z), f2bf(wL[1].w) };
      ushort8 pw1 = { f2bf(wL[2].x), f2bf(wL[2].y), f2bf(wL[2].z), f2bf(wL[2].w),
                      f2bf(wL[3].x), f2bf(wL[3].y), f2bf(wL[3].z), f2bf(wL[3].w) };
      *reinterpret_cast<ushort8*>(&As[srow][shalf])     = pa0;
      *reinterpret_cast<ushort8*>(&As[srow][shalf + 8]) = pa1;
      *reinterpret_cast<ushort8*>(&Bs[srow][shalf])     = pw0;
      *reinterpret_cast<ushort8*>(&Bs[srow][shalf + 8]) = pw1;
    }
    __syncthreads();

    if (it + 1 < NIT) {      // register prefetch of next K-slice, hidden under MFMAs
      const int kk0 = (it + 1) * BK;
      const int c = c0 + (kk0 >> 7);
      const int d0 = kk0 & 127;
      const float4* ap4 = reinterpret_cast<const float4*>(aBase + (long)c * 98304 + d0);
      const float4* wp4 = reinterpret_cast<const float4*>(wBase + (long)c * c_stride + d0);
#pragma unroll
      for (int q = 0; q < 4; ++q) { aL[q] = ap4[q]; wL[q] = wp4[q]; }
    }

    bf16x8 af[4], bf_[4];
#pragma unroll
    for (int i = 0; i < 4; ++i)
      af[i] = *reinterpret_cast<const bf16x8*>(&As[wm + 16 * i + lr][lq * 8]);
#pragma unroll
    for (int j = 0; j < 4; ++j)
      bf_[j] = *reinterpret_cast<const bf16x8*>(&Bs[wn + 16 * j + lr][lq * 8]);
#pragma unroll
    for (int i = 0; i < 4; ++i)
#pragma unroll
      for (int j = 0; j < 4; ++j)
        acc[i][j] = __builtin_amdgcn_mfma_f32_16x16x32_bf16(af[i], bf_[j], acc[i][j], 0, 0, 0);
  }

  // scatter-accumulate partials (D layout: row = lq*4+r, col = lr)
  float* cslot = conv + (long)slot * (NSLIDE * NBATCH);
#pragma unroll
  for (int i = 0; i < 4; ++i) {
#pragma unroll
    for (int j = 0; j < 4; ++j) {
#pragma unroll
      for (int r = 0; r < 4; ++r) {
        int s = m_half * 128 + wm + 16 * i + lq * 4 + r;
        int o = wn + 16 * j + lr;
        atomicAdd(&cslot[s * NBATCH + o], acc[i][j][r]);
      }
    }
  }
}

__global__ void epilogue(const float* __restrict__ conv,
                         const float* __restrict__ b1, const float* __restrict__ b2,
                         const float* __restrict__ b3, float* __restrict__ out)
{
  int t = blockIdx.x * 256 + threadIdx.x;   // 32768 threads: (s,o)
  int o = t & 127;
  int s = t >> 7;
  const float* base = conv + s * NBATCH + o;
  float r[16];
#pragma unroll
  for (int k = 0; k < 6; ++k) {   // h=1, kernels 3k
    float m = base[(3 * k + 0) * 32768];
    m = fmaxf(m, base[(3 * k + 1) * 32768]);
    m = fmaxf(m, base[(3 * k + 2) * 32768]);
    r[3 * k + 0] = fmaxf(m + b1[k * 128 + o], 0.f);
  }
#pragma unroll
  for (int k = 0; k < 5; ++k) {   // h=2, kernels 3k+1
    float m = fmaxf(base[(18 + 2 * k) * 32768], base[(18 + 2 * k + 1) * 32768]);
    r[3 * k + 1] = fmaxf(m + b2[k * 128 + o], 0.f);
  }
#pragma unroll
  for (int k = 0; k < 5; ++k) {   // h=3, kernels 3k+2
    r[3 * k + 2] = fmaxf(base[(28 + k) * 32768] + b3[k * 128 + o], 0.f);
  }
  float* op = out + ((long)o * 256 + s) * 16;   // out[B][S][1][K]
  reinterpret_cast<float4*>(op)[0] = make_float4(r[0], r[1], r[2], r[3]);
  reinterpret_cast<float4*>(op)[1] = make_float4(r[4], r[5], r[6], r[7]);
  reinterpret_cast<float4*>(op)[2] = make_float4(r[8], r[9], r[10], r[11]);
  reinterpret_cast<float4*>(op)[3] = make_float4(r[12], r[13], r[14], r[15]);
}

extern "C" void kernel_launch(void* const* d_in, const int* in_sizes, int n_in,
                              void* d_out, int out_size, void* d_ws, size_t ws_size,
                              hipStream_t stream) {
  const float* Ec = (const float*)d_in[0];
  const float* W1 = (const float*)d_in[1];
  const float* W2 = (const float*)d_in[2];
  const float* W3 = (const float*)d_in[3];
  const float* b1 = (const float*)d_in[4];
  const float* b2 = (const float*)d_in[5];
  const float* b3 = (const float*)d_in[6];
  float* out  = (float*)d_out;
  float* conv = (float*)d_ws;   // 33*256*128 floats = 4.33 MB

  zero_ws<<<CONV_ELEMS / 4 / 256, 256, 0, stream>>>(conv);          // 1056 blocks
  gemm_units<<<dim3(106, CCHUNKS), 256, 0, stream>>>(Ec, W1, W2, W3, conv);
  epilogue<<<(NSLIDE * NBATCH) / 256, 256, 0, stream>>>(conv, b1, b2, b3, out);
}